// Round 7
// baseline (51.613 us; speedup 1.0000x reference)
//
#include <hip/hip_runtime.h>
#include <math.h>

// OrthogonalButterfly: X (1024 x 8192) fp32, 20 butterfly layers, stride 2^(l%10).
// R6 lesson: lockstep-bound — no pipe >25% busy; block-wide barriers convoy
// 8-16 waves through alternating LDS/compute phases; all-scalar instr streams.
// R7: single-wave blocks (64 thr) owning 4 cols x 1024 rows; thread holds
// float4 y[16] (16 rows x 4 cols). __syncthreads is free at 1 wave -> 8-10
// fully independent waves/CU. All LDS/global ops are b128/dwordx4 (4x fewer
// instructions per pipe); cos/sin broadcast across the 4 cols.
// Same 5-phase / 4-transpose schedule + table build as R6 (passed).
// LDS 16KB/block; hash swizzle vrow = r ^ (((r>>3)^(r>>6))&7) hits the
// 8-lanes/bank-quad b128 floor on all five phase row-maps.
//
// Phase row maps (sub = lane in [0,64), element i in [0,16)):
//   P1: r = sub<<4 | i                         layers s=1,2,4,8    (SL=1,2,4,8)
//   P2: r = (sub&15) | i<<4 | (sub>>4)<<8      layers s=16..128    (SL=1,2,4,8)
//   P3: r = (i&3) | sub<<2 | (i>>2)<<8         layers s=256,512,1,2 (SL=4,8,1,2)
//   P4: r = (sub&3) | (i&3)<<2 | ((i>>2)&3)<<4 | (sub>>2)<<6
//                                              layers s=4..32      (SL=1,2,4,8)
//   P5: r = sub | (i&3)<<6 | (i>>2)<<8         layers s=64..512    (SL=1,2,4,8)

#define NROW   1024
#define BATCH  8192
#define BATCH4 (BATCH / 4)
#define DEPTH  20
#define NANG   512
#define TAB_ELEMS (DEPTH * NANG)
#define TAB_BYTES ((size_t)TAB_ELEMS * 8)

__device__ __host__ __forceinline__ int rowP1(int sub, int i){ return (sub<<4)|i; }
__device__ __host__ __forceinline__ int rowP2(int sub, int i){ return (sub&15) | (i<<4) | ((sub>>4)<<8); }
__device__ __host__ __forceinline__ int rowP3(int sub, int i){ return (i&3) | (sub<<2) | ((i>>2)<<8); }
__device__ __host__ __forceinline__ int rowP4(int sub, int i){ return (sub&3) | ((i&3)<<2) | (((i>>2)&3)<<4) | ((sub>>2)<<6); }
__device__ __host__ __forceinline__ int rowP5(int sub, int i){ return sub | ((i&3)<<6) | ((i>>2)<<8); }

// ---------------- angle table build (identical to R6, verified) ----------------
// slot = 8*sub + p. For layer l with local stride SL and phase row map,
// pair p -> local i0 = 2*(p/SL)*SL + p%SL -> row r -> original angle index
// a = (r >> (sp+1))*s + (r & (s-1)), s = 2^sp, sp = l%10.
__global__ void build_tab_kernel(const float* __restrict__ ang,
                                 float2* __restrict__ tab) {
    int idx = blockIdx.x * blockDim.x + threadIdx.x;
    if (idx >= TAB_ELEMS) return;
    int l = idx >> 9;
    int slot = idx & (NANG - 1);
    int sub = slot >> 3, p = slot & 7;
    int sp = l % 10;
    int SL, ph;
    if (l < 4)       { ph = 0; SL = 1 << l; }
    else if (l < 8)  { ph = 1; SL = 1 << (l - 4); }
    else if (l < 12) { ph = 2; SL = (l == 8) ? 4 : (l == 9) ? 8 : (l == 10) ? 1 : 2; }
    else if (l < 16) { ph = 3; SL = 1 << (l - 12); }
    else             { ph = 4; SL = 1 << (l - 16); }
    int i0 = 2 * (p / SL) * SL + p % SL;
    int r;
    if (ph == 0)      r = rowP1(sub, i0);
    else if (ph == 1) r = rowP2(sub, i0);
    else if (ph == 2) r = rowP3(sub, i0);
    else if (ph == 3) r = rowP4(sub, i0);
    else              r = rowP5(sub, i0);
    int s = 1 << sp;
    int a = ((r >> (sp + 1)) << sp) | (r & (s - 1));
    float th = ang[l * NANG + a];
    float sv, cv;
    sincosf(th, &sv, &cv);
    tab[idx] = make_float2(cv, sv);
}

// ---------------- main kernel ----------------
__device__ __forceinline__ void rot4(float4& a, float4& b, float cv, float sv) {
    float4 x0 = a, x1 = b;
    a.x = cv * x0.x + sv * x1.x;  b.x = cv * x1.x - sv * x0.x;
    a.y = cv * x0.y + sv * x1.y;  b.y = cv * x1.y - sv * x0.y;
    a.z = cv * x0.z + sv * x1.z;  b.z = cv * x1.z - sv * x0.z;
    a.w = cv * x0.w + sv * x1.w;  b.w = cv * x1.w - sv * x0.w;
}

// One layer on 16 register rows (each a float4 of 4 cols), local pair-stride SL.
// Table slice = 4 float4 at tl + 8*sub (8 cos/sin pairs).
template<int SL>
__device__ __forceinline__ void layer_tab(float4 y[16],
                                          const float2* __restrict__ tl,
                                          int sub) {
    const float4* q4 = reinterpret_cast<const float4*>(tl + 8 * sub);
    #pragma unroll
    for (int v = 0; v < 4; ++v) {
        float4 q = q4[v];
        int p0 = 2 * v, p1 = 2 * v + 1;
        int a0 = 2 * (p0 / SL) * SL + p0 % SL;   // constant-folds
        int a1 = 2 * (p1 / SL) * SL + p1 % SL;
        rot4(y[a0], y[a0 + SL], q.x, q.y);
        rot4(y[a1], y[a1 + SL], q.z, q.w);
    }
}

// Fallback without workspace: inline sincos (angles shared by the 4 cols).
template<int SL, int PH, int SP>
__device__ __forceinline__ void layer_notab(float4 y[16],
                                            const float* __restrict__ angL,
                                            int sub) {
    #pragma unroll
    for (int p = 0; p < 8; ++p) {
        int i0 = 2 * (p / SL) * SL + p % SL;
        int r;
        if (PH == 0)      r = rowP1(sub, i0);
        else if (PH == 1) r = rowP2(sub, i0);
        else if (PH == 2) r = rowP3(sub, i0);
        else if (PH == 3) r = rowP4(sub, i0);
        else              r = rowP5(sub, i0);
        int a = ((r >> (SP + 1)) << SP) | (r & ((1 << SP) - 1));
        float th = angL[a];
        float sv, cv;
        __sincosf(th, &sv, &cv);
        rot4(y[i0], y[i0 + SL], cv, sv);
    }
}

// LDS: 1024 float4 rows (16KB). Hash spreads b128 bank-quads for all phases.
__device__ __forceinline__ int vrow(int r) {
    return r ^ (((r >> 3) ^ (r >> 6)) & 7);
}

template<bool USE_TAB>
__global__ __launch_bounds__(64, 4) void butterfly_kernel(
        const float* __restrict__ X, const float* __restrict__ ang,
        const float2* __restrict__ tab, float* __restrict__ out) {
    __shared__ float4 lds4[NROW];        // 16 KB -> up to 10 blocks/CU
    int sub = threadIdx.x;               // [0,64) — block = exactly 1 wave
    int bid = blockIdx.x;
    int L = ((bid & 7) << 8) | (bid >> 3);   // XCD-aware, bijective (2048 = 8*256)
    int col0 = L << 2;                   // 4 consecutive columns per block

    float4 y[16];
    const float4* Xp = reinterpret_cast<const float4*>(X) + (col0 >> 2);
    #pragma unroll
    for (int i = 0; i < 16; ++i)
        y[i] = Xp[rowP1(sub, i) * BATCH4];

    if (USE_TAB) {
        layer_tab<1>(y, tab + 0 * NANG, sub);    // s=1
        layer_tab<2>(y, tab + 1 * NANG, sub);    // s=2
        layer_tab<4>(y, tab + 2 * NANG, sub);    // s=4
        layer_tab<8>(y, tab + 3 * NANG, sub);    // s=8
    } else {
        layer_notab<1,0,0>(y, ang + 0 * NANG, sub);
        layer_notab<2,0,1>(y, ang + 1 * NANG, sub);
        layer_notab<4,0,2>(y, ang + 2 * NANG, sub);
        layer_notab<8,0,3>(y, ang + 3 * NANG, sub);
    }
    // T1: wr P1 / rd P2
    #pragma unroll
    for (int i = 0; i < 16; ++i) lds4[vrow(rowP1(sub, i))] = y[i];
    __syncthreads();
    #pragma unroll
    for (int i = 0; i < 16; ++i) y[i] = lds4[vrow(rowP2(sub, i))];

    if (USE_TAB) {
        layer_tab<1>(y, tab + 4 * NANG, sub);    // s=16
        layer_tab<2>(y, tab + 5 * NANG, sub);    // s=32
        layer_tab<4>(y, tab + 6 * NANG, sub);    // s=64
        layer_tab<8>(y, tab + 7 * NANG, sub);    // s=128
    } else {
        layer_notab<1,1,4>(y, ang + 4 * NANG, sub);
        layer_notab<2,1,5>(y, ang + 5 * NANG, sub);
        layer_notab<4,1,6>(y, ang + 6 * NANG, sub);
        layer_notab<8,1,7>(y, ang + 7 * NANG, sub);
    }
    // T2: wr P2 / rd P3
    __syncthreads();
    #pragma unroll
    for (int i = 0; i < 16; ++i) lds4[vrow(rowP2(sub, i))] = y[i];
    __syncthreads();
    #pragma unroll
    for (int i = 0; i < 16; ++i) y[i] = lds4[vrow(rowP3(sub, i))];

    if (USE_TAB) {
        layer_tab<4>(y, tab +  8 * NANG, sub);   // s=256
        layer_tab<8>(y, tab +  9 * NANG, sub);   // s=512
        layer_tab<1>(y, tab + 10 * NANG, sub);   // s=1
        layer_tab<2>(y, tab + 11 * NANG, sub);   // s=2
    } else {
        layer_notab<4,2,8>(y, ang +  8 * NANG, sub);
        layer_notab<8,2,9>(y, ang +  9 * NANG, sub);
        layer_notab<1,2,0>(y, ang + 10 * NANG, sub);
        layer_notab<2,2,1>(y, ang + 11 * NANG, sub);
    }
    // T3: wr P3 / rd P4
    __syncthreads();
    #pragma unroll
    for (int i = 0; i < 16; ++i) lds4[vrow(rowP3(sub, i))] = y[i];
    __syncthreads();
    #pragma unroll
    for (int i = 0; i < 16; ++i) y[i] = lds4[vrow(rowP4(sub, i))];

    if (USE_TAB) {
        layer_tab<1>(y, tab + 12 * NANG, sub);   // s=4
        layer_tab<2>(y, tab + 13 * NANG, sub);   // s=8
        layer_tab<4>(y, tab + 14 * NANG, sub);   // s=16
        layer_tab<8>(y, tab + 15 * NANG, sub);   // s=32
    } else {
        layer_notab<1,3,2>(y, ang + 12 * NANG, sub);
        layer_notab<2,3,3>(y, ang + 13 * NANG, sub);
        layer_notab<4,3,4>(y, ang + 14 * NANG, sub);
        layer_notab<8,3,5>(y, ang + 15 * NANG, sub);
    }
    // T4: wr P4 / rd P5
    __syncthreads();
    #pragma unroll
    for (int i = 0; i < 16; ++i) lds4[vrow(rowP4(sub, i))] = y[i];
    __syncthreads();
    #pragma unroll
    for (int i = 0; i < 16; ++i) y[i] = lds4[vrow(rowP5(sub, i))];

    if (USE_TAB) {
        layer_tab<1>(y, tab + 16 * NANG, sub);   // s=64
        layer_tab<2>(y, tab + 17 * NANG, sub);   // s=128
        layer_tab<4>(y, tab + 18 * NANG, sub);   // s=256
        layer_tab<8>(y, tab + 19 * NANG, sub);   // s=512
    } else {
        layer_notab<1,4,6>(y, ang + 16 * NANG, sub);
        layer_notab<2,4,7>(y, ang + 17 * NANG, sub);
        layer_notab<4,4,8>(y, ang + 18 * NANG, sub);
        layer_notab<8,4,9>(y, ang + 19 * NANG, sub);
    }

    float4* Op = reinterpret_cast<float4*>(out) + (col0 >> 2);
    #pragma unroll
    for (int i = 0; i < 16; ++i)
        Op[rowP5(sub, i) * BATCH4] = y[i];
}

extern "C" void kernel_launch(void* const* d_in, const int* in_sizes, int n_in,
                              void* d_out, int out_size, void* d_ws, size_t ws_size,
                              hipStream_t stream) {
    (void)in_sizes; (void)n_in; (void)out_size;
    const float* X   = (const float*)d_in[0];
    const float* ang = (const float*)d_in[1];
    float* out = (float*)d_out;

    bool use_tab = (d_ws != nullptr) && (ws_size >= TAB_BYTES);
    if (use_tab) {
        float2* tab = (float2*)d_ws;
        build_tab_kernel<<<(TAB_ELEMS + 255) / 256, 256, 0, stream>>>(ang, tab);
        butterfly_kernel<true><<<2048, 64, 0, stream>>>(X, ang, tab, out);
    } else {
        butterfly_kernel<false><<<2048, 64, 0, stream>>>(X, ang, nullptr, out);
    }
}

// Round 8
// 36.786 us; speedup vs baseline: 1.4031x; 1.4031x over previous
//
#include <hip/hip_runtime.h>
#include <math.h>

// OrthogonalButterfly: X (1024 x 8192) fp32, 20 butterfly layers, stride 2^(l%10).
// R5=44us best (1024thr/16col/2blk-CU). R6 (512thr/8col) 56us, R7 (64thr/4col)
// 70us: perf tracks bytes-per-line-touch of global loads (64/32/16B) and
// barrier overlap. Instruction stream ~900/thread is the secondary floor.
// R8: float2 column-pairs. 512 thr = 8 float2-cols x 64 subs (16 real cols,
// same 64B/row coalescing as R5), y=float2[16], LDS 64KB -> 2 blocks/CU,
// 8-wave barriers, grid 512. Halves global/LDS/rot instruction count
// (dwordx2 / b64 / v_pk_fma-eligible). R6's verified 4-transpose schedule +
// table. Swizzle: e = c<<10 | (sigma(r) ^ (c<<1)), sigma(r)=r^((r>>4)&15)
// (involution) -> sub bits reach the bank index on all 5 phase maps; ~4
// lanes/bank-pair = b64 minimum.
//
// Phase row maps (sub in [0,64), i in [0,16)):
//   P1: r = sub<<4 | i                          layers s=1,2,4,8     (SL=1,2,4,8)
//   P2: r = (sub&15) | i<<4 | (sub>>4)<<8       layers s=16..128     (SL=1,2,4,8)
//   P3: r = (i&3) | sub<<2 | (i>>2)<<8          layers s=256,512,1,2 (SL=4,8,1,2)
//   P4: r = (sub&3) | (i&3)<<2 | ((i>>2)&3)<<4 | (sub>>2)<<6
//                                               layers s=4..32       (SL=1,2,4,8)
//   P5: r = sub | (i&3)<<6 | (i>>2)<<8          layers s=64..512     (SL=1,2,4,8)

#define NROW   1024
#define BATCH  8192
#define BATCH2 (BATCH / 2)
#define DEPTH  20
#define NANG   512
#define TAB_ELEMS (DEPTH * NANG)
#define TAB_BYTES ((size_t)TAB_ELEMS * 8)

__device__ __host__ __forceinline__ int rowP1(int sub, int i){ return (sub<<4)|i; }
__device__ __host__ __forceinline__ int rowP2(int sub, int i){ return (sub&15) | (i<<4) | ((sub>>4)<<8); }
__device__ __host__ __forceinline__ int rowP3(int sub, int i){ return (i&3) | (sub<<2) | ((i>>2)<<8); }
__device__ __host__ __forceinline__ int rowP4(int sub, int i){ return (sub&3) | ((i&3)<<2) | (((i>>2)&3)<<4) | ((sub>>2)<<6); }
__device__ __host__ __forceinline__ int rowP5(int sub, int i){ return sub | ((i&3)<<6) | ((i>>2)<<8); }

// ---------------- angle table build (identical to R6/R7, verified) ----------------
__global__ void build_tab_kernel(const float* __restrict__ ang,
                                 float2* __restrict__ tab) {
    int idx = blockIdx.x * blockDim.x + threadIdx.x;
    if (idx >= TAB_ELEMS) return;
    int l = idx >> 9;
    int slot = idx & (NANG - 1);
    int sub = slot >> 3, p = slot & 7;
    int sp = l % 10;
    int SL, ph;
    if (l < 4)       { ph = 0; SL = 1 << l; }
    else if (l < 8)  { ph = 1; SL = 1 << (l - 4); }
    else if (l < 12) { ph = 2; SL = (l == 8) ? 4 : (l == 9) ? 8 : (l == 10) ? 1 : 2; }
    else if (l < 16) { ph = 3; SL = 1 << (l - 12); }
    else             { ph = 4; SL = 1 << (l - 16); }
    int i0 = 2 * (p / SL) * SL + p % SL;
    int r;
    if (ph == 0)      r = rowP1(sub, i0);
    else if (ph == 1) r = rowP2(sub, i0);
    else if (ph == 2) r = rowP3(sub, i0);
    else if (ph == 3) r = rowP4(sub, i0);
    else              r = rowP5(sub, i0);
    int s = 1 << sp;
    int a = ((r >> (sp + 1)) << sp) | (r & (s - 1));
    float th = ang[l * NANG + a];
    float sv, cv;
    sincosf(th, &sv, &cv);
    tab[idx] = make_float2(cv, sv);
}

// ---------------- main kernel ----------------
__device__ __forceinline__ void rot2(float2& a, float2& b, float cv, float sv) {
    float2 x0 = a, x1 = b;
    a.x = cv * x0.x + sv * x1.x;  b.x = cv * x1.x - sv * x0.x;
    a.y = cv * x0.y + sv * x1.y;  b.y = cv * x1.y - sv * x0.y;
}

// One layer on 16 float2 rows, local pair-stride SL. Table slice = 4 float4
// at tl + 8*sub (8 cos/sin pairs, shared by the 8 c-lanes -> broadcast).
template<int SL>
__device__ __forceinline__ void layer_tab(float2 y[16],
                                          const float2* __restrict__ tl,
                                          int sub) {
    const float4* q4 = reinterpret_cast<const float4*>(tl + 8 * sub);
    #pragma unroll
    for (int v = 0; v < 4; ++v) {
        float4 q = q4[v];
        int p0 = 2 * v, p1 = 2 * v + 1;
        int a0 = 2 * (p0 / SL) * SL + p0 % SL;   // constant-folds
        int a1 = 2 * (p1 / SL) * SL + p1 % SL;
        rot2(y[a0], y[a0 + SL], q.x, q.y);
        rot2(y[a1], y[a1 + SL], q.z, q.w);
    }
}

// Fallback without workspace: inline sincos (angles shared by the 2 cols).
template<int SL, int PH, int SP>
__device__ __forceinline__ void layer_notab(float2 y[16],
                                            const float* __restrict__ angL,
                                            int sub) {
    #pragma unroll
    for (int p = 0; p < 8; ++p) {
        int i0 = 2 * (p / SL) * SL + p % SL;
        int r;
        if (PH == 0)      r = rowP1(sub, i0);
        else if (PH == 1) r = rowP2(sub, i0);
        else if (PH == 2) r = rowP3(sub, i0);
        else if (PH == 3) r = rowP4(sub, i0);
        else              r = rowP5(sub, i0);
        int a = ((r >> (SP + 1)) << SP) | (r & ((1 << SP) - 1));
        float th = angL[a];
        float sv, cv;
        __sincosf(th, &sv, &cv);
        rot2(y[i0], y[i0 + SL], cv, sv);
    }
}

// LDS element address for (float2-col c, row r). sigma is an involution; the
// (r>>4)&15 term pushes sub bits into the bank-pair index for every phase map;
// c<<1 decorrelates the 8 columns.
__device__ __forceinline__ int eaddr(int c, int r) {
    return (c << 10) | ((r ^ ((r >> 4) & 15)) ^ (c << 1));
}

template<bool USE_TAB>
__global__ __launch_bounds__(512) void butterfly_kernel(
        const float* __restrict__ X, const float* __restrict__ ang,
        const float2* __restrict__ tab, float* __restrict__ out) {
    __shared__ float2 lds2[8 * 1024];    // 64 KB -> 2 blocks/CU
    int t = threadIdx.x;
    int c = t & 7;                       // float2-column within block
    int sub = t >> 3;                    // [0,64)
    int bid = blockIdx.x;
    int L = ((bid & 7) << 6) | (bid >> 3);   // XCD-aware, bijective (512 = 8*64)
    int col2 = (L << 3) + c;             // float2-col in [0,4096)

    float2 y[16];
    const float2* Xp = reinterpret_cast<const float2*>(X) + col2;
    #pragma unroll
    for (int i = 0; i < 16; ++i)
        y[i] = Xp[rowP1(sub, i) * BATCH2];

    if (USE_TAB) {
        layer_tab<1>(y, tab + 0 * NANG, sub);    // s=1
        layer_tab<2>(y, tab + 1 * NANG, sub);    // s=2
        layer_tab<4>(y, tab + 2 * NANG, sub);    // s=4
        layer_tab<8>(y, tab + 3 * NANG, sub);    // s=8
    } else {
        layer_notab<1,0,0>(y, ang + 0 * NANG, sub);
        layer_notab<2,0,1>(y, ang + 1 * NANG, sub);
        layer_notab<4,0,2>(y, ang + 2 * NANG, sub);
        layer_notab<8,0,3>(y, ang + 3 * NANG, sub);
    }
    // T1: wr P1 / rd P2
    #pragma unroll
    for (int i = 0; i < 16; ++i) lds2[eaddr(c, rowP1(sub, i))] = y[i];
    __syncthreads();
    #pragma unroll
    for (int i = 0; i < 16; ++i) y[i] = lds2[eaddr(c, rowP2(sub, i))];

    if (USE_TAB) {
        layer_tab<1>(y, tab + 4 * NANG, sub);    // s=16
        layer_tab<2>(y, tab + 5 * NANG, sub);    // s=32
        layer_tab<4>(y, tab + 6 * NANG, sub);    // s=64
        layer_tab<8>(y, tab + 7 * NANG, sub);    // s=128
    } else {
        layer_notab<1,1,4>(y, ang + 4 * NANG, sub);
        layer_notab<2,1,5>(y, ang + 5 * NANG, sub);
        layer_notab<4,1,6>(y, ang + 6 * NANG, sub);
        layer_notab<8,1,7>(y, ang + 7 * NANG, sub);
    }
    // T2: wr P2 / rd P3
    __syncthreads();
    #pragma unroll
    for (int i = 0; i < 16; ++i) lds2[eaddr(c, rowP2(sub, i))] = y[i];
    __syncthreads();
    #pragma unroll
    for (int i = 0; i < 16; ++i) y[i] = lds2[eaddr(c, rowP3(sub, i))];

    if (USE_TAB) {
        layer_tab<4>(y, tab +  8 * NANG, sub);   // s=256
        layer_tab<8>(y, tab +  9 * NANG, sub);   // s=512
        layer_tab<1>(y, tab + 10 * NANG, sub);   // s=1
        layer_tab<2>(y, tab + 11 * NANG, sub);   // s=2
    } else {
        layer_notab<4,2,8>(y, ang +  8 * NANG, sub);
        layer_notab<8,2,9>(y, ang +  9 * NANG, sub);
        layer_notab<1,2,0>(y, ang + 10 * NANG, sub);
        layer_notab<2,2,1>(y, ang + 11 * NANG, sub);
    }
    // T3: wr P3 / rd P4
    __syncthreads();
    #pragma unroll
    for (int i = 0; i < 16; ++i) lds2[eaddr(c, rowP3(sub, i))] = y[i];
    __syncthreads();
    #pragma unroll
    for (int i = 0; i < 16; ++i) y[i] = lds2[eaddr(c, rowP4(sub, i))];

    if (USE_TAB) {
        layer_tab<1>(y, tab + 12 * NANG, sub);   // s=4
        layer_tab<2>(y, tab + 13 * NANG, sub);   // s=8
        layer_tab<4>(y, tab + 14 * NANG, sub);   // s=16
        layer_tab<8>(y, tab + 15 * NANG, sub);   // s=32
    } else {
        layer_notab<1,3,2>(y, ang + 12 * NANG, sub);
        layer_notab<2,3,3>(y, ang + 13 * NANG, sub);
        layer_notab<4,3,4>(y, ang + 14 * NANG, sub);
        layer_notab<8,3,5>(y, ang + 15 * NANG, sub);
    }
    // T4: wr P4 / rd P5
    __syncthreads();
    #pragma unroll
    for (int i = 0; i < 16; ++i) lds2[eaddr(c, rowP4(sub, i))] = y[i];
    __syncthreads();
    #pragma unroll
    for (int i = 0; i < 16; ++i) y[i] = lds2[eaddr(c, rowP5(sub, i))];

    if (USE_TAB) {
        layer_tab<1>(y, tab + 16 * NANG, sub);   // s=64
        layer_tab<2>(y, tab + 17 * NANG, sub);   // s=128
        layer_tab<4>(y, tab + 18 * NANG, sub);   // s=256
        layer_tab<8>(y, tab + 19 * NANG, sub);   // s=512
    } else {
        layer_notab<1,4,6>(y, ang + 16 * NANG, sub);
        layer_notab<2,4,7>(y, ang + 17 * NANG, sub);
        layer_notab<4,4,8>(y, ang + 18 * NANG, sub);
        layer_notab<8,4,9>(y, ang + 19 * NANG, sub);
    }

    float2* Op = reinterpret_cast<float2*>(out) + col2;
    #pragma unroll
    for (int i = 0; i < 16; ++i)
        Op[rowP5(sub, i) * BATCH2] = y[i];
}

extern "C" void kernel_launch(void* const* d_in, const int* in_sizes, int n_in,
                              void* d_out, int out_size, void* d_ws, size_t ws_size,
                              hipStream_t stream) {
    (void)in_sizes; (void)n_in; (void)out_size;
    const float* X   = (const float*)d_in[0];
    const float* ang = (const float*)d_in[1];
    float* out = (float*)d_out;

    bool use_tab = (d_ws != nullptr) && (ws_size >= TAB_BYTES);
    if (use_tab) {
        float2* tab = (float2*)d_ws;
        build_tab_kernel<<<(TAB_ELEMS + 255) / 256, 256, 0, stream>>>(ang, tab);
        butterfly_kernel<true><<<512, 512, 0, stream>>>(X, ang, tab, out);
    } else {
        butterfly_kernel<false><<<512, 512, 0, stream>>>(X, ang, nullptr, out);
    }
}